// Round 1
// baseline (151.420 us; speedup 1.0000x reference)
//
#include <hip/hip_runtime.h>

// P1 (CG1) function evaluation on a triangular mesh.
// out[i] = c0*(1-s-t) + c1*s + c2*t where (s,t) = (x[i]-A[c]) @ Minv[c], c = cell_ids[i].
//
// Memory-bound gather kernel: stream x (float2/pt), cell_ids, out; gather
// Minv/A/dofs/weight (9.5 MB total -> L2/L3 resident).
// 2 points per thread => float4/int2/float2 coalesced streaming accesses.

__global__ __launch_bounds__(256) void p1_eval_kernel(
    const float*  __restrict__ x,        // (N_PTS, 2)
    const float*  __restrict__ Minv,     // (N_CELLS, 2, 2) row-major
    const float*  __restrict__ A,        // (N_CELLS, 2)
    const float*  __restrict__ weight,   // (N_DOFS,)
    const int*    __restrict__ cell_ids, // (N_PTS,)
    const int*    __restrict__ dofs,     // (N_CELLS, 3)
    float*        __restrict__ out,      // (N_PTS,)
    int n_pairs)                          // N_PTS / 2
{
    int i = blockIdx.x * blockDim.x + threadIdx.x;
    if (i >= n_pairs) return;

    // Streaming loads: 2 points per thread.
    float4 p2 = ((const float4*)x)[i];          // x/y of point 2i, x/y of point 2i+1
    int2   c2 = ((const int2*)cell_ids)[i];

    float r[2];
    #pragma unroll
    for (int k = 0; k < 2; ++k) {
        int c = (k == 0) ? c2.x : c2.y;
        float px = (k == 0) ? p2.x : p2.z;
        float py = (k == 0) ? p2.y : p2.w;

        float2 a = ((const float2*)A)[c];
        float4 M = ((const float4*)Minv)[c];    // m00, m01, m10, m11
        float dx = px - a.x;
        float dy = py - a.y;
        float s = dx * M.x + dy * M.z;          // st[0] = dx*m00 + dy*m10
        float t = dx * M.y + dy * M.w;          // st[1] = dx*m01 + dy*m11

        int d0 = dofs[c * 3 + 0];
        int d1 = dofs[c * 3 + 1];
        int d2 = dofs[c * 3 + 2];
        float c0 = weight[d0];
        float c1 = weight[d1];
        float cc2 = weight[d2];

        r[k] = c0 * (1.0f - s - t) + c1 * s + cc2 * t;
    }

    ((float2*)out)[i] = make_float2(r[0], r[1]);
}

extern "C" void kernel_launch(void* const* d_in, const int* in_sizes, int n_in,
                              void* d_out, int out_size, void* d_ws, size_t ws_size,
                              hipStream_t stream) {
    const float* x        = (const float*)d_in[0];
    const float* Minv     = (const float*)d_in[1];
    const float* A        = (const float*)d_in[2];
    const float* weight   = (const float*)d_in[3];
    const int*   cell_ids = (const int*)d_in[4];
    const int*   dofs     = (const int*)d_in[5];
    float*       out      = (float*)d_out;

    int n_pts = out_size;            // 4194304
    int n_pairs = n_pts / 2;         // even by construction
    int block = 256;
    int grid = (n_pairs + block - 1) / block;
    p1_eval_kernel<<<grid, block, 0, stream>>>(x, Minv, A, weight, cell_ids, dofs, out, n_pairs);
}

// Round 2
// 42.899 us; speedup vs baseline: 3.5297x; 3.5297x over previous
//
#include <hip/hip_runtime.h>

// P1 (CG1) function evaluation, two-pass affine-collapse version.
//
// Pass 1 (precompute, per cell): out = alpha + beta*px + gamma*py with
//   w1 = c1-c0, w2 = c2-c0
//   beta  = m00*w1 + m01*w2
//   gamma = m10*w1 + m11*w2
//   alpha = c0 - ax*beta - ay*gamma
// Reads Minv/A/dofs/weight coalesced ONCE (9.5 MB), writes 3 MB table.
//
// Pass 2 (per point): one 12 B gather from the 3 MB table (fits per-XCD 4 MB
// L2), streaming x/cell_ids/out with non-temporal hints so the table stays
// L2-resident. Round-1 counters showed 530 MB FETCH (5 random lines/pt,
// capacity misses); this cuts gather traffic ~6x.

typedef float  f4 __attribute__((ext_vector_type(4)));
typedef float  f2 __attribute__((ext_vector_type(2)));
typedef int    i2 __attribute__((ext_vector_type(2)));

__global__ __launch_bounds__(256) void p1_precompute_kernel(
    const float* __restrict__ Minv,    // (N_CELLS, 2, 2)
    const float* __restrict__ A,       // (N_CELLS, 2)
    const float* __restrict__ weight,  // (N_DOFS,)
    const int*   __restrict__ dofs,    // (N_CELLS, 3)
    float*       __restrict__ table,   // (N_CELLS, 3) = alpha, beta, gamma
    int n_cells)
{
    int c = blockIdx.x * blockDim.x + threadIdx.x;
    if (c >= n_cells) return;

    f4 M = ((const f4*)Minv)[c];       // m00, m01, m10, m11
    f2 a = ((const f2*)A)[c];
    int d0 = dofs[3 * c + 0];
    int d1 = dofs[3 * c + 1];
    int d2 = dofs[3 * c + 2];
    float c0 = weight[d0];
    float c1 = weight[d1];
    float c2 = weight[d2];

    float w1 = c1 - c0, w2 = c2 - c0;
    float beta  = M.x * w1 + M.y * w2;
    float gamma = M.z * w1 + M.w * w2;
    float alpha = c0 - a.x * beta - a.y * gamma;

    table[3 * c + 0] = alpha;
    table[3 * c + 1] = beta;
    table[3 * c + 2] = gamma;
}

__global__ __launch_bounds__(256) void p1_eval_fast(
    const float* __restrict__ x,         // (N_PTS, 2)
    const int*   __restrict__ cell_ids,  // (N_PTS,)
    const float* __restrict__ table,     // (N_CELLS, 3)
    float*       __restrict__ out,       // (N_PTS,)
    int n_pairs)
{
    int i = blockIdx.x * blockDim.x + threadIdx.x;
    if (i >= n_pairs) return;

    // Non-temporal streaming loads: don't pollute L2 (table must stay resident).
    f4 p2 = __builtin_nontemporal_load((const f4*)x + i);
    i2 c2 = __builtin_nontemporal_load((const i2*)cell_ids + i);

    const float* t0 = table + 3 * (long)c2.x;
    const float* t1 = table + 3 * (long)c2.y;
    float a0 = t0[0], b0 = t0[1], g0 = t0[2];
    float a1 = t1[0], b1 = t1[1], g1 = t1[2];

    f2 r;
    r.x = a0 + p2.x * b0 + p2.y * g0;
    r.y = a1 + p2.z * b1 + p2.w * g1;

    __builtin_nontemporal_store(r, (f2*)out + i);
}

// Fallback (round-1 kernel) in case ws_size is too small for the table.
__global__ __launch_bounds__(256) void p1_eval_direct(
    const float* __restrict__ x,
    const float* __restrict__ Minv,
    const float* __restrict__ A,
    const float* __restrict__ weight,
    const int*   __restrict__ cell_ids,
    const int*   __restrict__ dofs,
    float*       __restrict__ out,
    int n_pairs)
{
    int i = blockIdx.x * blockDim.x + threadIdx.x;
    if (i >= n_pairs) return;
    f4 p2 = ((const f4*)x)[i];
    i2 c2 = ((const i2*)cell_ids)[i];
    float r[2];
    #pragma unroll
    for (int k = 0; k < 2; ++k) {
        int c = (k == 0) ? c2.x : c2.y;
        float px = (k == 0) ? p2.x : p2.z;
        float py = (k == 0) ? p2.y : p2.w;
        f2 a = ((const f2*)A)[c];
        f4 M = ((const f4*)Minv)[c];
        float dx = px - a.x, dy = py - a.y;
        float s = dx * M.x + dy * M.z;
        float t = dx * M.y + dy * M.w;
        float c0 = weight[dofs[c * 3 + 0]];
        float c1 = weight[dofs[c * 3 + 1]];
        float cc = weight[dofs[c * 3 + 2]];
        r[k] = c0 * (1.0f - s - t) + c1 * s + cc * t;
    }
    f2 rv; rv.x = r[0]; rv.y = r[1];
    ((f2*)out)[i] = rv;
}

extern "C" void kernel_launch(void* const* d_in, const int* in_sizes, int n_in,
                              void* d_out, int out_size, void* d_ws, size_t ws_size,
                              hipStream_t stream) {
    const float* x        = (const float*)d_in[0];
    const float* Minv     = (const float*)d_in[1];
    const float* A        = (const float*)d_in[2];
    const float* weight   = (const float*)d_in[3];
    const int*   cell_ids = (const int*)d_in[4];
    const int*   dofs     = (const int*)d_in[5];
    float*       out      = (float*)d_out;

    int n_pts   = out_size;          // 4194304
    int n_cells = in_sizes[2] / 2;   // A has 2 floats per cell -> 262144
    int n_pairs = n_pts / 2;
    int block = 256;

    size_t table_bytes = (size_t)n_cells * 3 * sizeof(float);

    if (ws_size >= table_bytes) {
        float* table = (float*)d_ws;
        int grid_pre = (n_cells + block - 1) / block;
        p1_precompute_kernel<<<grid_pre, block, 0, stream>>>(
            Minv, A, weight, dofs, table, n_cells);
        int grid_main = (n_pairs + block - 1) / block;
        p1_eval_fast<<<grid_main, block, 0, stream>>>(
            x, cell_ids, table, out, n_pairs);
    } else {
        int grid = (n_pairs + block - 1) / block;
        p1_eval_direct<<<grid, block, 0, stream>>>(
            x, Minv, A, weight, cell_ids, dofs, out, n_pairs);
    }
}